// Round 5
// baseline (56.591 us; speedup 1.0000x reference)
//
#include <hip/hip_runtime.h>
#include <hip/hip_bf16.h>

#define HH 8
#define SEQL 4096
#define DD 128
#define NBLK 64
#define LOCAL_B 16
#define MBIAS 12.0f
#define EP_STR 132

typedef __attribute__((ext_vector_type(8))) short bf16x8;
typedef __attribute__((ext_vector_type(4))) float f32x4;
typedef unsigned short ushort_t;

typedef const __attribute__((address_space(1))) unsigned int gu32;
typedef __attribute__((address_space(3))) unsigned int lu32;

__device__ __forceinline__ unsigned short f2bf(float x) {
    union { float f; unsigned u; } a; a.f = x;
    unsigned r = a.u + 0x7FFFu + ((a.u >> 16) & 1u);
    return (unsigned short)(r >> 16);
}

__device__ __forceinline__ unsigned cvtpk_bf16(float lo, float hi) {
    unsigned r;
    asm("v_cvt_pk_bf16_f32 %0, %1, %2" : "=v"(r) : "v"(lo), "v"(hi));
    return r;
}

__device__ __forceinline__ void gload16(const void* src, void* ldsdst) {
    __builtin_amdgcn_global_load_lds((gu32*)src, (lu32*)ldsdst, 16, 0, 0);
}

// ---------------- fused prepass: K f32->bf16 flat; V f32 [H][S][D] -> bf16 Vt [H][D][S] ----------------
#define T_STR 136
__global__ void prep(const float* __restrict__ k, const float* __restrict__ v,
                     ushort_t* __restrict__ kb, ushort_t* __restrict__ vt) {
    __shared__ ushort_t t[64 * T_STR];
    int bid = blockIdx.x;
    int tid = threadIdx.x;
    if (bid < 2048) {
        int idx = (bid * 256 + tid) * 8;
        const float4* s = (const float4*)(k + idx);
        float4 a = s[0], b = s[1];
        union { bf16x8 v8; ushort_t u[8]; } p;
        p.u[0] = f2bf(a.x); p.u[1] = f2bf(a.y); p.u[2] = f2bf(a.z); p.u[3] = f2bf(a.w);
        p.u[4] = f2bf(b.x); p.u[5] = f2bf(b.y); p.u[6] = f2bf(b.z); p.u[7] = f2bf(b.w);
        *(bf16x8*)(kb + idx) = p.v8;
        return;
    }
    int g = bid - 2048;
    int h  = g >> 6;
    int sb = g & 63;
    const float* vp = v + ((size_t)h * SEQL + sb * 64) * DD;
    {
        int col = (tid & 15) * 8;
        #pragma unroll
        for (int it = 0; it < 4; ++it) {
            int row = it * 16 + (tid >> 4);
            const float4* s = (const float4*)(vp + row * DD + col);
            float4 a = s[0], b = s[1];
            union { bf16x8 v8; ushort_t u[8]; } p;
            p.u[0] = f2bf(a.x); p.u[1] = f2bf(a.y); p.u[2] = f2bf(a.z); p.u[3] = f2bf(a.w);
            p.u[4] = f2bf(b.x); p.u[5] = f2bf(b.y); p.u[6] = f2bf(b.z); p.u[7] = f2bf(b.w);
            *(bf16x8*)&t[row * T_STR + col] = p.v8;
        }
    }
    __syncthreads();
    {
        int d = tid >> 1, seg = tid & 1;
        ushort_t* dst = vt + ((size_t)h * DD + d) * SEQL + sb * 64 + seg * 32;
        #pragma unroll
        for (int i = 0; i < 4; ++i) {
            union { bf16x8 v8; ushort_t u[8]; } o;
            #pragma unroll
            for (int e = 0; e < 8; ++e)
                o.u[e] = t[(seg * 32 + i * 8 + e) * T_STR + d];
            *(bf16x8*)(dst + i * 8) = o.v8;
        }
    }
}

// ---------------- main attention kernel ----------------
__global__ __launch_bounds__(256, 2)
void bsattn5(const float* __restrict__ q, const ushort_t* __restrict__ kbuf,
             const ushort_t* __restrict__ vtbuf, const float* __restrict__ scl,
             float* __restrict__ out) {
    const int g  = blockIdx.x;
    const int h  = g & 7;
    const int i0 = g >> 3;
    const int qb = (i0 < 32) ? (63 - i0) : (i0 - 32);
    const int tid = threadIdx.x;
    const int w  = tid >> 6;
    const int l  = tid & 63;
    const int lr = l & 15;
    const int lg = l >> 4;

    __shared__ char smem[65536];
    // K dbuf: [0, 32768)  (64 rows x 256B, swizzled)
    // V dbuf: [32768, 65536) (128 rows x 128B, swizzled)
    // epilogue reuses smem as float [4][16][EP_STR]

    const float kappa = scl[0] * 1.44269504088896f;

    const float*    qh = q     + (size_t)h * SEQL * DD;
    const ushort_t* kh = kbuf  + (size_t)h * SEQL * DD;
    const ushort_t* vh = vtbuf + (size_t)h * DD * SEQL;
    float*          oh = out   + (size_t)h * SEQL * DD;

    // Q -> B-fragments, prescaled by kappa (wave w owns q cols 16w..16w+15)
    bf16x8 qf[4];
    {
        const float* qrow = qh + (size_t)(qb * 64 + 16 * w + lr) * DD;
        #pragma unroll
        for (int ks = 0; ks < 4; ++ks) {
            const float4* p4 = (const float4*)(qrow + ks * 32 + lg * 8);
            float4 x = p4[0], y = p4[1];
            union { bf16x8 v8; ushort_t u[8]; } pk;
            pk.u[0] = f2bf(x.x * kappa); pk.u[1] = f2bf(x.y * kappa);
            pk.u[2] = f2bf(x.z * kappa); pk.u[3] = f2bf(x.w * kappa);
            pk.u[4] = f2bf(y.x * kappa); pk.u[5] = f2bf(y.y * kappa);
            pk.u[6] = f2bf(y.z * kappa); pk.u[7] = f2bf(y.w * kappa);
            qf[ks] = pk.v8;
        }
    }

    f32x4 oacc[8];   // O^T: row d = 16dt+4lg+j, col q = lr
    #pragma unroll
    for (int i = 0; i < 8; ++i) oacc[i] = (f32x4){0.f, 0.f, 0.f, 0.f};
    float lrun = 0.f;

    // loop-carried swizzled LDS read bases (flip 16384 per iter)
    unsigned swz = (unsigned)((lg * 16) ^ ((lr & 7) << 4));
    unsigned kA = (unsigned)(lr * 256) + swz;
    unsigned kB = kA ^ 64u;
    unsigned vA = 32768u + (unsigned)(lr * 128) + swz;
    unsigned vB = vA ^ 64u;
    // stage destination parity (wave-uniform)
    unsigned kst = 0, vst = 0;

    auto stage = [&](int kb) {
        const char* kbase = (const char*)(kh + (size_t)kb * 64 * DD);
        char* kdst = smem + kst;
        #pragma unroll
        for (int j = 0; j < 4; ++j) {
            int row  = w * 16 + j * 4 + (l >> 4);
            int colb = ((l & 15) << 4) ^ ((row & 7) << 4);
            gload16(kbase + row * 256 + colb, kdst + (w * 16 + j * 4) * 256);
        }
        const char* vbase = (const char*)vh + (size_t)kb * 128;
        char* vdst = smem + 32768 + vst;
        #pragma unroll
        for (int j = 0; j < 4; ++j) {
            int d0 = w * 32 + j * 8;
            int d  = d0 + (l >> 3);
            int colb = ((l & 7) << 4) ^ ((d & 7) << 4);
            gload16(vbase + (size_t)d * (SEQL * 2) + colb, vdst + d0 * 128);
        }
        kst ^= 16384u; vst ^= 16384u;
    };

    const bool selA = (lg >= 2);
    const bool b1 = (lg & 1);
    const bool b2 = (lg & 2);

    auto compute = [&](bool diag) {
        // S^T = K Q^T : row k = 16ct+4lg+j, col q = lr; C-init = -MBIAS
        f32x4 sacc[4];
        #pragma unroll
        for (int ct = 0; ct < 4; ++ct)
            sacc[ct] = (f32x4){-MBIAS, -MBIAS, -MBIAS, -MBIAS};
        __builtin_amdgcn_s_setprio(1);
        #pragma unroll
        for (int ks = 0; ks < 4; ++ks) {
            #pragma unroll
            for (int ct = 0; ct < 4; ++ct) {
                bf16x8 kf = *(const bf16x8*)(smem + ((ks & 1) ? kB : kA) +
                                             ct * 4096 + (ks >> 1) * 128);
                sacc[ct] = __builtin_amdgcn_mfma_f32_16x16x32_bf16(kf, qf[ks], sacc[ct], 0, 0, 0);
            }
        }
        __builtin_amdgcn_s_setprio(0);

        // p = exp2(S^T - M); zero masked entries AFTER exp (diag only)
        float p[4][4];
        #pragma unroll
        for (int ct = 0; ct < 4; ++ct)
            #pragma unroll
            for (int j = 0; j < 4; ++j)
                p[ct][j] = exp2f(sacc[ct][j]);
        if (diag) {
            #pragma unroll
            for (int ct = 0; ct < 4; ++ct)
                #pragma unroll
                for (int j = 0; j < 4; ++j)
                    if (16 * ct + 4 * lg + j > 16 * w + lr) p[ct][j] = 0.f;
        }
        float rs = 0.f;
        #pragma unroll
        for (int ct = 0; ct < 4; ++ct)
            #pragma unroll
            for (int j = 0; j < 4; ++j) rs += p[ct][j];
        lrun += rs;

        // pack P to bf16 pairs
        unsigned e0 = cvtpk_bf16(p[0][0], p[0][1]), e1 = cvtpk_bf16(p[0][2], p[0][3]);
        unsigned e2 = cvtpk_bf16(p[2][0], p[2][1]), e3 = cvtpk_bf16(p[2][2], p[2][3]);
        unsigned o0 = cvtpk_bf16(p[1][0], p[1][1]), o1 = cvtpk_bf16(p[1][2], p[1][3]);
        unsigned o2 = cvtpk_bf16(p[3][0], p[3][1]), o3 = cvtpk_bf16(p[3][2], p[3][3]);

        // single-level butterfly: 3 independent shuffles per chain + quarter selects
        union { unsigned u[4]; bf16x8 v8; } pb0, pb1;
        {
            unsigned m = selA ? o0 : e0, n = selA ? e0 : o0;
            unsigned t  = __shfl_xor((int)n, 32);
            unsigned tp = __shfl_xor((int)n, 48);
            unsigned m16 = __shfl_xor((int)m, 16);
            pb0.u[0] = b1 ? (b2 ? m16 : tp) : (b2 ? t : m);
            pb0.u[2] = b1 ? (b2 ? m : t) : (b2 ? tp : m16);
        }
        {
            unsigned m = selA ? o1 : e1, n = selA ? e1 : o1;
            unsigned t  = __shfl_xor((int)n, 32);
            unsigned tp = __shfl_xor((int)n, 48);
            unsigned m16 = __shfl_xor((int)m, 16);
            pb0.u[1] = b1 ? (b2 ? m16 : tp) : (b2 ? t : m);
            pb0.u[3] = b1 ? (b2 ? m : t) : (b2 ? tp : m16);
        }
        {
            unsigned m = selA ? o2 : e2, n = selA ? e2 : o2;
            unsigned t  = __shfl_xor((int)n, 32);
            unsigned tp = __shfl_xor((int)n, 48);
            unsigned m16 = __shfl_xor((int)m, 16);
            pb1.u[0] = b1 ? (b2 ? m16 : tp) : (b2 ? t : m);
            pb1.u[2] = b1 ? (b2 ? m : t) : (b2 ? tp : m16);
        }
        {
            unsigned m = selA ? o3 : e3, n = selA ? e3 : o3;
            unsigned t  = __shfl_xor((int)n, 32);
            unsigned tp = __shfl_xor((int)n, 48);
            unsigned m16 = __shfl_xor((int)m, 16);
            pb1.u[1] = b1 ? (b2 ? m16 : tp) : (b2 ? t : m);
            pb1.u[3] = b1 ? (b2 ? m : t) : (b2 ? tp : m16);
        }

        // O^T += Vt P
        __builtin_amdgcn_s_setprio(1);
        #pragma unroll
        for (int dt = 0; dt < 8; ++dt) {
            bf16x8 vf = *(const bf16x8*)(smem + vA + dt * 2048);
            oacc[dt] = __builtin_amdgcn_mfma_f32_16x16x32_bf16(vf, pb0.v8, oacc[dt], 0, 0, 0);
        }
        #pragma unroll
        for (int dt = 0; dt < 8; ++dt) {
            bf16x8 vf = *(const bf16x8*)(smem + vB + dt * 2048);
            oacc[dt] = __builtin_amdgcn_mfma_f32_16x16x32_bf16(vf, pb1.v8, oacc[dt], 0, 0, 0);
        }
        __builtin_amdgcn_s_setprio(0);
    };

    // iterate active k blocks: verticals, local band, diagonal last
    const int vstart = (7 - h) & 7;
    int lo = qb - (LOCAL_B - 1); if (lo < 0) lo = 0;
    int kb = (vstart <= qb - LOCAL_B) ? vstart : lo;
    stage(kb);
    for (;;) {
        int kn;
        if (kb < lo) { int n = kb + 8; kn = (n <= qb - LOCAL_B) ? n : lo; }
        else if (kb < qb) kn = kb + 1;
        else kn = -1;

        if (kn >= 0) {
            stage(kn);
            asm volatile("s_waitcnt vmcnt(8)" ::: "memory");
            __builtin_amdgcn_sched_barrier(0);
            __builtin_amdgcn_s_barrier();
            __builtin_amdgcn_sched_barrier(0);
            compute(false);
            __builtin_amdgcn_s_barrier();
            kA ^= 16384u; kB ^= 16384u; vA ^= 16384u; vB ^= 16384u;
            kb = kn;
        } else {
            asm volatile("s_waitcnt vmcnt(0)" ::: "memory");
            __builtin_amdgcn_sched_barrier(0);
            __builtin_amdgcn_s_barrier();
            __builtin_amdgcn_sched_barrier(0);
            compute(true);
            __builtin_amdgcn_s_barrier();
            break;
        }
    }

    // epilogue: finish row sums, normalize, transpose via LDS for coalesced stores
    float tot = lrun;
    tot += __shfl_xor(tot, 16);
    tot += __shfl_xor(tot, 32);
    float rcp = 1.0f / tot;

    float* ep  = (float*)smem;
    float* epw = ep + w * 16 * EP_STR;
    #pragma unroll
    for (int dt = 0; dt < 8; ++dt)
        #pragma unroll
        for (int j = 0; j < 4; ++j)
            epw[lr * EP_STR + dt * 16 + 4 * lg + j] = oacc[dt][j] * rcp;
    __syncthreads();
    {
        int qr  = tid >> 2;
        int seg = tid & 3;
        const float* rp = ep + (qr >> 4) * (16 * EP_STR) + (qr & 15) * EP_STR + seg * 32;
        float* op = oh + (size_t)(qb * 64 + qr) * DD + seg * 32;
        #pragma unroll
        for (int i = 0; i < 8; ++i)
            ((float4*)op)[i] = ((const float4*)rp)[i];
    }
}

extern "C" void kernel_launch(void* const* d_in, const int* in_sizes, int n_in,
                              void* d_out, int out_size, void* d_ws, size_t ws_size,
                              hipStream_t stream) {
    const float* q   = (const float*)d_in[0];
    const float* k   = (const float*)d_in[1];
    const float* v   = (const float*)d_in[2];
    const float* scl = (const float*)d_in[3];
    float* out = (float*)d_out;

    ushort_t* Kb = (ushort_t*)d_ws;                          // 8 MB bf16 K
    ushort_t* Vt = Kb + (size_t)HH * SEQL * DD;              // 8 MB bf16 V^T

    prep<<<dim3(2048 + HH * 64), dim3(256), 0, stream>>>(k, v, Kb, Vt);
    bsattn5<<<dim3(HH * NBLK), dim3(256), 0, stream>>>(q, Kb, Vt, scl, out);
}